// Round 3
// baseline (1722.505 us; speedup 1.0000x reference)
//
#include <hip/hip_runtime.h>
#include <math.h>

// ---------------------------------------------------------------------------
// MoE transformer block. Round 3: audited consolidation of the round-2 design.
//   LN1(split-bf16 out) -> qkv split-bf16 MFMA -> fp32 flash attn (ctx hi/lo)
//   -> proj split-bf16 MFMA (+resid -> d_out) -> LN2 (f32 + bf16 out)
//   -> fp32 gate/top2 -> prefix+loss
//   -> fc1 bf16 MFMA (gather, GELU, bf16 out) -> fc2 bf16 MFMA (scatter f32)
// Precision plan: split-bf16 (Ah*Bh+Ah*Bl+Al*Bh, ~2e-5 rel) on the large-
// magnitude path; plain bf16 on experts (output ~0.017 scale -> ~1e-4 abs);
// router/LN/softmax fp32 (top-2 selection is discrete -> must match ref).
// ---------------------------------------------------------------------------

typedef float f4v __attribute__((ext_vector_type(4)));
typedef __attribute__((ext_vector_type(8))) short bf16x8;   // 8 bf16 = 4 VGPR
typedef __attribute__((ext_vector_type(4))) float f32x4;    // MFMA acc
typedef __attribute__((ext_vector_type(4))) unsigned short u16x4;
typedef unsigned short u16;

#define NTOK   4096
#define SEQ    2048
#define DMODEL 1024
#define NH     16
#define NE     8
#define DFF    4096

// ---- bf16 helpers (RN-even) ------------------------------------------------
__device__ __forceinline__ u16 f2bf(float f) {
  unsigned u = __float_as_uint(f);
  unsigned r = (u + 0x7fffu + ((u >> 16) & 1u)) >> 16;
  return (u16)r;
}
__device__ __forceinline__ float bf2f(u16 h) {
  return __uint_as_float(((unsigned)h) << 16);
}
__device__ __forceinline__ float gelu_tanh(float x) {
  return 0.5f * x * (1.0f + tanhf(0.7978845608028654f * (x + 0.044715f * x * x * x)));
}

// async global->LDS, 16B per lane. Audited: every call site computes the LDS
// dest as wave_base + lane*16B (linear), per the m104/m108 HW constraint.
__device__ __forceinline__ void async16(void* lds, const void* g) {
  __builtin_amdgcn_global_load_lds(
      (const __attribute__((address_space(1))) unsigned int*)g,
      (__attribute__((address_space(3))) unsigned int*)lds, 16, 0, 0);
}

// ---------------- LayerNorm: fp32 row LN, selectable output formats ---------
template<bool WF32, bool WSPLIT, bool WPLAIN>
__global__ __launch_bounds__(256)
void ln_kernel(const float* __restrict__ x, const float* __restrict__ g,
               const float* __restrict__ bta, float* __restrict__ y,
               u16* __restrict__ yhi, u16* __restrict__ ylo,
               u16* __restrict__ yb) {
  const int row = blockIdx.x;
  const int tid = threadIdx.x;
  const size_t base = (size_t)row * DMODEL + tid * 4;
  f4v v = *(const f4v*)&x[base];
  float s  = v[0] + v[1] + v[2] + v[3];
  float s2 = v[0]*v[0] + v[1]*v[1] + v[2]*v[2] + v[3]*v[3];
#pragma unroll
  for (int off = 32; off > 0; off >>= 1) {
    s  += __shfl_xor(s,  off);
    s2 += __shfl_xor(s2, off);
  }
  __shared__ float red[8];
  const int w = tid >> 6, lane = tid & 63;
  if (lane == 0) { red[w] = s; red[4 + w] = s2; }
  __syncthreads();
  s  = red[0] + red[1] + red[2] + red[3];
  s2 = red[4] + red[5] + red[6] + red[7];
  const float mu  = s * (1.0f / DMODEL);
  const float var = s2 * (1.0f / DMODEL) - mu * mu;  // ddof=0, matches jnp.var
  const float rs  = rsqrtf(var + 1e-5f);
  f4v gv = *(const f4v*)&g[tid * 4];
  f4v bv = *(const f4v*)&bta[tid * 4];
  float o[4];
#pragma unroll
  for (int i = 0; i < 4; ++i) o[i] = (v[i] - mu) * rs * gv[i] + bv[i];
  if (WF32) {
    f4v ov = {o[0], o[1], o[2], o[3]};
    *(f4v*)&y[base] = ov;
  }
  if (WSPLIT) {
    u16x4 hv, lv;
#pragma unroll
    for (int i = 0; i < 4; ++i) {
      hv[i] = f2bf(o[i]);
      lv[i] = f2bf(o[i] - bf2f(hv[i]));
    }
    *(u16x4*)&yhi[base] = hv;
    *(u16x4*)&ylo[base] = lv;
  }
  if (WPLAIN) {
    u16x4 bb;
#pragma unroll
    for (int i = 0; i < 4; ++i) bb[i] = f2bf(o[i]);
    *(u16x4*)&yb[base] = bb;
  }
}

// ---------------- fp32 -> bf16 conversions (weights) ------------------------
__global__ __launch_bounds__(256)
void convert_split(const float* __restrict__ src, u16* __restrict__ hi,
                   u16* __restrict__ lo) {
  const size_t i = ((size_t)blockIdx.x * 256 + threadIdx.x) * 4;
  f4v v = *(const f4v*)&src[i];
  u16x4 hv, lv;
#pragma unroll
  for (int j = 0; j < 4; ++j) {
    hv[j] = f2bf(v[j]);
    lv[j] = f2bf(v[j] - bf2f(hv[j]));
  }
  *(u16x4*)&hi[i] = hv;
  *(u16x4*)&lo[i] = lv;
}

__global__ __launch_bounds__(256)
void convert_bf16(const float* __restrict__ src, u16* __restrict__ dst) {
  const size_t i = ((size_t)blockIdx.x * 256 + threadIdx.x) * 4;
  f4v v = *(const f4v*)&src[i];
  u16x4 b;
#pragma unroll
  for (int j = 0; j < 4; ++j) b[j] = f2bf(v[j]);
  *(u16x4*)&dst[i] = b;
}

// ---------------- split-bf16 MFMA GEMM: C = A*B^T (3-term hi/lo) ------------
// A: [M][K] hi/lo bf16, B: [N][K] hi/lo bf16, C fp32 (+optional resid).
// 128x128 tile, BK=32, 4 waves (2x2), 4x4 16x16x32 frags/wave, 48 MFMA/step.
template<bool RESID>
__global__ __launch_bounds__(256)
void gemm_split(const u16* __restrict__ Ah, const u16* __restrict__ Al,
                const u16* __restrict__ Bh, const u16* __restrict__ Bl,
                float* __restrict__ C, const float* __restrict__ resid,
                int N, int K) {
  __shared__ u16 sA[2][128 * 32];
  __shared__ u16 sB[2][128 * 32];
  const int t = threadIdx.x;
  const int m0 = blockIdx.y * 128, n0 = blockIdx.x * 128;
  const int srow = t >> 2, scol = (t & 3) * 8;      // lds dest = t*8 elems = lane*16B ✓
  const size_t ga0 = (size_t)(m0 + srow) * K + scol;
  const size_t ga1 = (size_t)(m0 + 64 + srow) * K + scol;
  const size_t gb0 = (size_t)(n0 + srow) * K + scol;
  const size_t gb1 = (size_t)(n0 + 64 + srow) * K + scol;
  const int ld0 = srow * 32 + scol;
  const int ld1 = (64 + srow) * 32 + scol;
  const int w = t >> 6, lane = t & 63;
  const int wr = (w >> 1) * 64, wc = (w & 1) * 64;
  const int lr = lane & 15, lk = (lane >> 4) * 8;   // A/B frag: row=lane&15, k=(lane>>4)*8
  f32x4 acc[4][4] = {};
  for (int k0 = 0; k0 < K; k0 += 32) {
    async16(&sA[0][ld0], Ah + ga0 + k0);
    async16(&sA[0][ld1], Ah + ga1 + k0);
    async16(&sA[1][ld0], Al + ga0 + k0);
    async16(&sA[1][ld1], Al + ga1 + k0);
    async16(&sB[0][ld0], Bh + gb0 + k0);
    async16(&sB[0][ld1], Bh + gb1 + k0);
    async16(&sB[1][ld0], Bl + gb0 + k0);
    async16(&sB[1][ld1], Bl + gb1 + k0);
    __syncthreads();                                 // compiler drains vmcnt
    bf16x8 ah[4], al[4], bh[4], bl[4];
#pragma unroll
    for (int m = 0; m < 4; ++m) {
      ah[m] = *(const bf16x8*)&sA[0][(wr + m * 16 + lr) * 32 + lk];
      al[m] = *(const bf16x8*)&sA[1][(wr + m * 16 + lr) * 32 + lk];
    }
#pragma unroll
    for (int n = 0; n < 4; ++n) {
      bh[n] = *(const bf16x8*)&sB[0][(wc + n * 16 + lr) * 32 + lk];
      bl[n] = *(const bf16x8*)&sB[1][(wc + n * 16 + lr) * 32 + lk];
    }
#pragma unroll
    for (int m = 0; m < 4; ++m)
#pragma unroll
      for (int n = 0; n < 4; ++n) {
        acc[m][n] = __builtin_amdgcn_mfma_f32_16x16x32_bf16(al[m], bh[n], acc[m][n], 0, 0, 0);
        acc[m][n] = __builtin_amdgcn_mfma_f32_16x16x32_bf16(ah[m], bl[n], acc[m][n], 0, 0, 0);
        acc[m][n] = __builtin_amdgcn_mfma_f32_16x16x32_bf16(ah[m], bh[n], acc[m][n], 0, 0, 0);
      }
    __syncthreads();
  }
  const int crow = (lane >> 4) * 4;  // D: col=lane&15, row=(lane>>4)*4+reg [m89]
#pragma unroll
  for (int m = 0; m < 4; ++m)
#pragma unroll
    for (int r = 0; r < 4; ++r) {
      const int row = m0 + wr + m * 16 + crow + r;
#pragma unroll
      for (int n = 0; n < 4; ++n) {
        const int col = n0 + wc + n * 16 + lr;
        const size_t o = (size_t)row * N + col;
        float v = acc[m][n][r];
        if (RESID) v += resid[o];
        C[o] = v;
      }
    }
}

// ---------------- flash attention, fp32 (Q-tile 32, K-tile 64) --------------
// Writes ctx as split hi/lo bf16 for the proj GEMM.
__global__ __launch_bounds__(256)
void attn_kernel(const float* __restrict__ qkv, u16* __restrict__ ctx_hi,
                 u16* __restrict__ ctx_lo) {
  const int qt = blockIdx.x;
  const int h  = blockIdx.y;
  const int b  = blockIdx.z;
  __shared__ float Qs[32][64];
  __shared__ float Ks[64][68];  // +4 pad: K-read lanes spread 8 banks (vs 1 unpadded)
  __shared__ float Vs[64][64];
  __shared__ float Ps[32][64];
  const int tid = threadIdx.x;
  const int rg = tid >> 4;      // 2 q-rows per thread
  const int cc = tid & 15;      // 4 key-cols / 4 d-cols per thread
  const int qbase = qt * 32;

  for (int idx = tid; idx < 32 * 16; idx += 256) {
    int r = idx >> 4, c4 = (idx & 15) * 4;
    *(f4v*)&Qs[r][c4] =
        *(const f4v*)&qkv[((size_t)(b * SEQ + qbase + r)) * 3072 + h * 64 + c4];
  }
  float O[2][4] = {};
  float mrow[2] = {-1e30f, -1e30f};
  float lrow[2] = {0.f, 0.f};
  const int ktmax = qt >> 1;

  for (int kt = 0; kt <= ktmax; ++kt) {
    __syncthreads();
    for (int idx = tid; idx < 64 * 16; idx += 256) {
      int r = idx >> 4, c4 = (idx & 15) * 4;
      size_t rowoff = ((size_t)(b * SEQ + kt * 64 + r)) * 3072 + h * 64 + c4;
      *(f4v*)&Ks[r][c4] = *(const f4v*)&qkv[rowoff + 1024];
      *(f4v*)&Vs[r][c4] = *(const f4v*)&qkv[rowoff + 2048];
    }
    __syncthreads();

    float s[2][4] = {};
#pragma unroll
    for (int d0 = 0; d0 < 64; d0 += 4) {
      f4v q4[2], k4[4];
      q4[0] = *(const f4v*)&Qs[rg * 2 + 0][d0];   // uniform per 16-lane group: broadcast
      q4[1] = *(const f4v*)&Qs[rg * 2 + 1][d0];
#pragma unroll
      for (int j = 0; j < 4; ++j) k4[j] = *(const f4v*)&Ks[cc * 4 + j][d0];
#pragma unroll
      for (int i = 0; i < 2; ++i)
#pragma unroll
        for (int j = 0; j < 4; ++j)
          s[i][j] += q4[i][0]*k4[j][0] + q4[i][1]*k4[j][1] +
                     q4[i][2]*k4[j][2] + q4[i][3]*k4[j][3];
    }

    const bool diag = (kt == ktmax);
#pragma unroll
    for (int i = 0; i < 2; ++i) {
      const int qoff = (qt & 1) * 32 + rg * 2 + i;  // local row within 64-key frame
#pragma unroll
      for (int j = 0; j < 4; ++j) {
        float sv = s[i][j] * 0.125f;                // 1/sqrt(64)
        if (diag && (cc * 4 + j > qoff)) sv = -1e30f;
        s[i][j] = sv;
      }
    }
    float rmax[2];
#pragma unroll
    for (int i = 0; i < 2; ++i)
      rmax[i] = fmaxf(fmaxf(s[i][0], s[i][1]), fmaxf(s[i][2], s[i][3]));
#pragma unroll
    for (int off = 1; off < 16; off <<= 1) {
      rmax[0] = fmaxf(rmax[0], __shfl_xor(rmax[0], off));
      rmax[1] = fmaxf(rmax[1], __shfl_xor(rmax[1], off));
    }
    float rsum[2];
#pragma unroll
    for (int i = 0; i < 2; ++i) {
      const float mnew = fmaxf(mrow[i], rmax[i]);
      const float corr = __expf(mrow[i] - mnew);
      float su = 0.f;
#pragma unroll
      for (int j = 0; j < 4; ++j) { s[i][j] = __expf(s[i][j] - mnew); su += s[i][j]; }
      rsum[i] = su;
      mrow[i] = mnew;
      lrow[i] *= corr;
#pragma unroll
      for (int j = 0; j < 4; ++j) O[i][j] *= corr;
    }
#pragma unroll
    for (int off = 1; off < 16; off <<= 1) {
      rsum[0] += __shfl_xor(rsum[0], off);
      rsum[1] += __shfl_xor(rsum[1], off);
    }
    lrow[0] += rsum[0]; lrow[1] += rsum[1];
#pragma unroll
    for (int i = 0; i < 2; ++i) {
      f4v pv = {s[i][0], s[i][1], s[i][2], s[i][3]};
      *(f4v*)&Ps[rg * 2 + i][cc * 4] = pv;
    }
    __syncthreads();
#pragma unroll
    for (int c0 = 0; c0 < 64; c0 += 4) {
      f4v p4[2], v4[4];
      p4[0] = *(const f4v*)&Ps[rg * 2 + 0][c0];
      p4[1] = *(const f4v*)&Ps[rg * 2 + 1][c0];
#pragma unroll
      for (int cj = 0; cj < 4; ++cj) v4[cj] = *(const f4v*)&Vs[c0 + cj][cc * 4];
#pragma unroll
      for (int i = 0; i < 2; ++i)
#pragma unroll
        for (int j = 0; j < 4; ++j)
          O[i][j] += p4[i][0]*v4[0][j] + p4[i][1]*v4[1][j] +
                     p4[i][2]*v4[2][j] + p4[i][3]*v4[3][j];
    }
  }
#pragma unroll
  for (int i = 0; i < 2; ++i) {
    const float inv = 1.0f / lrow[i];
    u16x4 hv, lv;
#pragma unroll
    for (int j = 0; j < 4; ++j) {
      float v = O[i][j] * inv;
      hv[j] = f2bf(v);
      lv[j] = f2bf(v - bf2f(hv[j]));
    }
    const size_t off = ((size_t)(b * SEQ + qbase + rg * 2 + i)) * DMODEL + h * 64 + cc * 4;
    *(u16x4*)&ctx_hi[off] = hv;
    *(u16x4*)&ctx_lo[off] = lv;
  }
}

// ---------------- router: fp32 gate logits + top-2 + list build -------------
// f32 on purpose: top-2 selection is discrete; bf16 logits (~1e-3 err) would
// flip near-tie tokens vs the reference. Tie-break = lowest index, like top_k.
__global__ __launch_bounds__(256)
void gate_kernel(const float* __restrict__ m, const float* __restrict__ gw,
                 int* __restrict__ epos, int* __restrict__ toklist,
                 float* __restrict__ wlist) {
  const int tid = threadIdx.x;
  const int t = blockIdx.x * 4 + (tid >> 6);  // one wave per token
  const int lane = tid & 63;
  float part[NE] = {};
  for (int d0 = lane * 4; d0 < DMODEL; d0 += 256) {
    f4v mv = *(const f4v*)&m[(size_t)t * DMODEL + d0];
#pragma unroll
    for (int e = 0; e < NE; ++e) {
      f4v gv = *(const f4v*)&gw[e * DMODEL + d0];
      part[e] += mv[0]*gv[0] + mv[1]*gv[1] + mv[2]*gv[2] + mv[3]*gv[3];
    }
  }
#pragma unroll
  for (int e = 0; e < NE; ++e)
#pragma unroll
    for (int off = 32; off > 0; off >>= 1) part[e] += __shfl_xor(part[e], off);
  if (lane == 0) {
    int e0 = 0; float v0 = part[0];
#pragma unroll
    for (int e = 1; e < NE; ++e) if (part[e] > v0) { v0 = part[e]; e0 = e; }
    int e1 = -1; float v1 = -3.4e38f;
#pragma unroll
    for (int e = 0; e < NE; ++e)
      if (e != e0 && part[e] > v1) { v1 = part[e]; e1 = e; }
    const float w0 = 1.0f / (1.0f + __expf(v1 - v0));  // softmax([v0,v1]), v0>=v1
    const float w1 = 1.0f - w0;
    int p0 = atomicAdd(&epos[e0], 1);
    toklist[e0 * 4096 + p0] = t; wlist[e0 * 4096 + p0] = w0;
    int p1 = atomicAdd(&epos[e1], 1);
    toklist[e1 * 4096 + p1] = t; wlist[e1 * 4096 + p1] = w1;
  }
}

__global__ void zero_epos(int* __restrict__ p) { p[threadIdx.x] = 0; }

// prefix offsets + router aux loss (single thread; counts sum to 8192 exactly)
__global__ void prefix_loss(const int* __restrict__ epos, int* __restrict__ eoff,
                            float* __restrict__ lossout) {
  int off = 0;
  float c[NE], sum = 0.f;
  for (int e = 0; e < NE; ++e) {
    eoff[e] = off; off += epos[e];
    c[e] = (float)epos[e]; sum += c[e];
  }
  const float mean = sum / NE;
  float var = 0.f;
  for (int e = 0; e < NE; ++e) var += (c[e] - mean) * (c[e] - mean);
  var *= (1.0f / (NE - 1));  // ddof=1
  lossout[0] = 0.01f * sqrtf(var) / (mean + 1e-6f);
}

// ---------------- expert fc1: h1 = gelu(gather(m_bf16) @ fc1_bf16[e]^T) -----
// plain bf16 MFMA, gathered A rows, bf16 output (compacted rows).
// MFMA row-independence keeps tail-row garbage confined to discarded outputs.
__global__ __launch_bounds__(256)
void gemm_fc1(const u16* __restrict__ mb, const u16* __restrict__ fc1b,
              const int* __restrict__ toklist, const int* __restrict__ epos,
              const int* __restrict__ eoff, u16* __restrict__ h1) {
  const int e = blockIdx.z;
  const int cnt = epos[e];
  const int m0 = blockIdx.y * 128;
  if (m0 >= cnt) return;                     // also guards cnt==0 clamp below
  const int n0 = blockIdx.x * 128;
  __shared__ u16 sA[128 * 32];
  __shared__ u16 sB[128 * 32];
  const int t = threadIdx.x;
  const int srow = t >> 2, scol = (t & 3) * 8;
  const int p0 = m0 + srow, p1 = m0 + 64 + srow;
  const int tok0 = toklist[e * 4096 + (p0 < cnt ? p0 : cnt - 1)];
  const int tok1 = toklist[e * 4096 + (p1 < cnt ? p1 : cnt - 1)];
  const size_t ga0 = (size_t)tok0 * DMODEL + scol;
  const size_t ga1 = (size_t)tok1 * DMODEL + scol;
  const size_t gb0 = (size_t)e * DFF * DMODEL + (size_t)(n0 + srow) * DMODEL + scol;
  const size_t gb1 = gb0 + (size_t)64 * DMODEL;
  const int ld0 = srow * 32 + scol;
  const int ld1 = (64 + srow) * 32 + scol;
  const int w = t >> 6, lane = t & 63;
  const int wr = (w >> 1) * 64, wc = (w & 1) * 64;
  const int lr = lane & 15, lk = (lane >> 4) * 8;
  f32x4 acc[4][4] = {};
  for (int k0 = 0; k0 < DMODEL; k0 += 32) {
    async16(&sA[ld0], mb + ga0 + k0);
    async16(&sA[ld1], mb + ga1 + k0);
    async16(&sB[ld0], fc1b + gb0 + k0);
    async16(&sB[ld1], fc1b + gb1 + k0);
    __syncthreads();
    bf16x8 a[4], bb[4];
#pragma unroll
    for (int m = 0; m < 4; ++m) a[m] = *(const bf16x8*)&sA[(wr + m * 16 + lr) * 32 + lk];
#pragma unroll
    for (int n = 0; n < 4; ++n) bb[n] = *(const bf16x8*)&sB[(wc + n * 16 + lr) * 32 + lk];
#pragma unroll
    for (int m = 0; m < 4; ++m)
#pragma unroll
      for (int n = 0; n < 4; ++n)
        acc[m][n] = __builtin_amdgcn_mfma_f32_16x16x32_bf16(a[m], bb[n], acc[m][n], 0, 0, 0);
    __syncthreads();
  }
  const int base = eoff[e];
  const int crow = (lane >> 4) * 4;
#pragma unroll
  for (int m = 0; m < 4; ++m)
#pragma unroll
    for (int r = 0; r < 4; ++r) {
      const int pr = m0 + wr + m * 16 + crow + r;
      if (pr < cnt) {
#pragma unroll
        for (int n = 0; n < 4; ++n) {
          const int col = n0 + wc + n * 16 + lr;
          h1[(size_t)(base + pr) * DFF + col] = f2bf(gelu_tanh(acc[m][n][r]));
        }
      }
    }
}

// ---------------- expert fc2: out += w * (h1 @ fc2_bf16[e]^T) ---------------
__global__ __launch_bounds__(256)
void gemm_fc2(const u16* __restrict__ h1, const u16* __restrict__ fc2b,
              const int* __restrict__ toklist, const float* __restrict__ wlist,
              const int* __restrict__ epos, const int* __restrict__ eoff,
              float* __restrict__ out) {
  const int e = blockIdx.z;
  const int cnt = epos[e];
  const int m0 = blockIdx.y * 128;
  if (m0 >= cnt) return;
  const int n0 = blockIdx.x * 128;
  __shared__ u16 sA[128 * 32];
  __shared__ u16 sB[128 * 32];
  const int t = threadIdx.x;
  const int srow = t >> 2, scol = (t & 3) * 8;
  const int base = eoff[e];
  const size_t ga0 = (size_t)(base + m0 + srow) * DFF + scol;  // slack rows alloc'd
  const size_t ga1 = ga0 + (size_t)64 * DFF;
  const size_t gb0 = (size_t)e * DMODEL * DFF + (size_t)(n0 + srow) * DFF + scol;
  const size_t gb1 = gb0 + (size_t)64 * DFF;
  const int ld0 = srow * 32 + scol;
  const int ld1 = (64 + srow) * 32 + scol;
  const int w = t >> 6, lane = t & 63;
  const int wr = (w >> 1) * 64, wc = (w & 1) * 64;
  const int lr = lane & 15, lk = (lane >> 4) * 8;
  f32x4 acc[4][4] = {};
  for (int k0 = 0; k0 < DFF; k0 += 32) {
    async16(&sA[ld0], h1 + ga0 + k0);
    async16(&sA[ld1], h1 + ga1 + k0);
    async16(&sB[ld0], fc2b + gb0 + k0);
    async16(&sB[ld1], fc2b + gb1 + k0);
    __syncthreads();
    bf16x8 a[4], bb[4];
#pragma unroll
    for (int m = 0; m < 4; ++m) a[m] = *(const bf16x8*)&sA[(wr + m * 16 + lr) * 32 + lk];
#pragma unroll
    for (int n = 0; n < 4; ++n) bb[n] = *(const bf16x8*)&sB[(wc + n * 16 + lr) * 32 + lk];
#pragma unroll
    for (int m = 0; m < 4; ++m)
#pragma unroll
      for (int n = 0; n < 4; ++n)
        acc[m][n] = __builtin_amdgcn_mfma_f32_16x16x32_bf16(a[m], bb[n], acc[m][n], 0, 0, 0);
    __syncthreads();
  }
  const int crow = (lane >> 4) * 4;
#pragma unroll
  for (int m = 0; m < 4; ++m)
#pragma unroll
    for (int r = 0; r < 4; ++r) {
      const int pr = m0 + wr + m * 16 + crow + r;
      if (pr < cnt) {
        const int tok = toklist[e * 4096 + pr];
        const float wgt = wlist[e * 4096 + pr];
        float* dst = out + (size_t)tok * DMODEL + n0 + wc;
#pragma unroll
        for (int n = 0; n < 4; ++n)
          atomicAdd(&dst[n * 16 + lr], wgt * acc[m][n][r]);
      }
    }
}

// ---------------------------------------------------------------------------
extern "C" void kernel_launch(void* const* d_in, const int* in_sizes, int n_in,
                              void* d_out, int out_size, void* d_ws, size_t ws_size,
                              hipStream_t stream) {
  const float* x     = (const float*)d_in[0];
  const float* ln1g  = (const float*)d_in[1];
  const float* ln1b  = (const float*)d_in[2];
  const float* wqkv  = (const float*)d_in[3];
  const float* wproj = (const float*)d_in[4];
  const float* ln2g  = (const float*)d_in[5];
  const float* ln2b  = (const float*)d_in[6];
  const float* gw    = (const float*)d_in[7];
  const float* fc1   = (const float*)d_in[8];
  const float* fc2   = (const float*)d_in[9];
  float* out = (float*)d_out;

  char* p = (char*)d_ws;
  auto alloc = [&](size_t bytes) {
    void* r = (void*)p;
    p += (bytes + 255) & ~(size_t)255;
    return r;
  };
  u16*   h_hi    = (u16*)alloc((size_t)NTOK * DMODEL * 2);
  u16*   h_lo    = (u16*)alloc((size_t)NTOK * DMODEL * 2);
  float* qkv     = (float*)alloc((size_t)NTOK * 3 * DMODEL * 4);
  u16*   ctx_hi  = (u16*)alloc((size_t)NTOK * DMODEL * 2);
  u16*   ctx_lo  = (u16*)alloc((size_t)NTOK * DMODEL * 2);
  float* m_f32   = (float*)alloc((size_t)NTOK * DMODEL * 4);
  u16*   m_bf16  = (u16*)alloc((size_t)NTOK * DMODEL * 2);
  u16*   wqkv_hi = (u16*)alloc((size_t)3 * DMODEL * DMODEL * 2);
  u16*   wqkv_lo = (u16*)alloc((size_t)3 * DMODEL * DMODEL * 2);
  u16*   wproj_hi= (u16*)alloc((size_t)DMODEL * DMODEL * 2);
  u16*   wproj_lo= (u16*)alloc((size_t)DMODEL * DMODEL * 2);
  u16*   fc1b    = (u16*)alloc((size_t)NE * DFF * DMODEL * 2);
  u16*   fc2b    = (u16*)alloc((size_t)NE * DMODEL * DFF * 2);
  u16*   h1      = (u16*)alloc((size_t)(2 * NTOK + 128) * DFF * 2);
  float* wlist   = (float*)alloc((size_t)NE * 4096 * 4);
  int*   toklist = (int*)alloc((size_t)NE * 4096 * 4);
  int*   epos    = (int*)alloc(64);
  int*   eoff    = (int*)alloc(64);

  zero_epos<<<1, 8, 0, stream>>>(epos);
  // weight conversions (grids cover n/1024 blocks; all sizes % 1024 == 0)
  convert_split<<<3 * DMODEL * DMODEL / 1024, 256, 0, stream>>>(wqkv, wqkv_hi, wqkv_lo);
  convert_split<<<DMODEL * DMODEL / 1024, 256, 0, stream>>>(wproj, wproj_hi, wproj_lo);
  convert_bf16<<<NE * DFF * DMODEL / 1024, 256, 0, stream>>>(fc1, fc1b);
  convert_bf16<<<NE * DMODEL * DFF / 1024, 256, 0, stream>>>(fc2, fc2b);

  // LN1 -> split bf16
  ln_kernel<false, true, false><<<NTOK, 256, 0, stream>>>(x, ln1g, ln1b,
      nullptr, h_hi, h_lo, nullptr);
  // qkv = h @ wqkv^T  (split-bf16 MFMA)
  gemm_split<false><<<dim3(24, 32), 256, 0, stream>>>(h_hi, h_lo, wqkv_hi, wqkv_lo,
                                                      qkv, nullptr, 3 * DMODEL, DMODEL);
  attn_kernel<<<dim3(64, NH, 2), 256, 0, stream>>>(qkv, ctx_hi, ctx_lo);
  // out = x + ctx @ wproj^T  (split-bf16 MFMA, resid add; experts atomicAdd later)
  gemm_split<true><<<dim3(8, 32), 256, 0, stream>>>(ctx_hi, ctx_lo, wproj_hi, wproj_lo,
                                                    out, x, DMODEL, DMODEL);
  // LN2 -> fp32 (gate) + plain bf16 (experts)
  ln_kernel<true, false, true><<<NTOK, 256, 0, stream>>>(out, ln2g, ln2b,
      m_f32, nullptr, nullptr, m_bf16);
  gate_kernel<<<NTOK / 4, 256, 0, stream>>>(m_f32, gw, epos, toklist, wlist);
  prefix_loss<<<1, 1, 0, stream>>>(epos, eoff, out + (size_t)NTOK * DMODEL);
  gemm_fc1<<<dim3(DFF / 128, 32, NE), 256, 0, stream>>>(m_bf16, fc1b, toklist,
                                                        epos, eoff, h1);
  gemm_fc2<<<dim3(DMODEL / 128, 32, NE), 256, 0, stream>>>(h1, fc2b, toklist, wlist,
                                                           epos, eoff, out);
}

// Round 8
// 1019.561 us; speedup vs baseline: 1.6895x; 1.6895x over previous
//
#include <hip/hip_runtime.h>
#include <math.h>

// ---------------------------------------------------------------------------
// MoE transformer block. Round 8: fifth submission of the round-4 design
// (GPU timeouts; no data on it yet); audits clean, occupancy checked.
// Single experimental delta vs the measured round-3 kernel (1722us, passed):
// MFMA flash attention replacing the fp32 bank-conflict-bound attn (944us).
//   LN1(split-bf16) -> qkv split-bf16 MFMA (epilogue emits Q/K split head-major
//   + swizzled K/Vt tiles) -> attn: MFMA flash (QK^T split-bf16, PV bf16)
//   -> proj split-bf16 MFMA (+resid -> d_out) -> LN2 -> fp32 gate/top2
//   -> fc1 bf16 MFMA (gather, GELU) -> fc2 bf16 MFMA (scatter f32 atomics)
// Attention LDS uses the T2-style XOR swizzle; K/Vt tiles are PRE-swizzled in
// global so global_load_lds (linear dest) + swizzled ds_read is conflict-free.
// ---------------------------------------------------------------------------

typedef float f4v __attribute__((ext_vector_type(4)));
typedef __attribute__((ext_vector_type(8))) short bf16x8;   // 8 bf16 = 4 VGPR
typedef __attribute__((ext_vector_type(4))) float f32x4;    // MFMA acc
typedef __attribute__((ext_vector_type(4))) unsigned short u16x4;
typedef unsigned short u16;

#define NTOK   4096
#define SEQ    2048
#define DMODEL 1024
#define NH     16
#define NE     8
#define DFF    4096

// ---- bf16 helpers (RN-even) ------------------------------------------------
__device__ __forceinline__ u16 f2bf(float f) {
  unsigned u = __float_as_uint(f);
  unsigned r = (u + 0x7fffu + ((u >> 16) & 1u)) >> 16;
  return (u16)r;
}
__device__ __forceinline__ float bf2f(u16 h) {
  return __uint_as_float(((unsigned)h) << 16);
}
__device__ __forceinline__ float gelu_tanh(float x) {
  return 0.5f * x * (1.0f + tanhf(0.7978845608028654f * (x + 0.044715f * x * x * x)));
}

// async global->LDS, 16B per lane (linear dest = wave base + lane*16B).
__device__ __forceinline__ void async16(void* lds, const void* g) {
  __builtin_amdgcn_global_load_lds(
      (const __attribute__((address_space(1))) unsigned int*)g,
      (__attribute__((address_space(3))) unsigned int*)lds, 16, 0, 0);
}

// ---------------- LayerNorm: fp32 row LN, selectable output formats ---------
template<bool WF32, bool WSPLIT, bool WPLAIN>
__global__ __launch_bounds__(256)
void ln_kernel(const float* __restrict__ x, const float* __restrict__ g,
               const float* __restrict__ bta, float* __restrict__ y,
               u16* __restrict__ yhi, u16* __restrict__ ylo,
               u16* __restrict__ yb) {
  const int row = blockIdx.x;
  const int tid = threadIdx.x;
  const size_t base = (size_t)row * DMODEL + tid * 4;
  f4v v = *(const f4v*)&x[base];
  float s  = v[0] + v[1] + v[2] + v[3];
  float s2 = v[0]*v[0] + v[1]*v[1] + v[2]*v[2] + v[3]*v[3];
#pragma unroll
  for (int off = 32; off > 0; off >>= 1) {
    s  += __shfl_xor(s,  off);
    s2 += __shfl_xor(s2, off);
  }
  __shared__ float red[8];
  const int w = tid >> 6, lane = tid & 63;
  if (lane == 0) { red[w] = s; red[4 + w] = s2; }
  __syncthreads();
  s  = red[0] + red[1] + red[2] + red[3];
  s2 = red[4] + red[5] + red[6] + red[7];
  const float mu  = s * (1.0f / DMODEL);
  const float var = s2 * (1.0f / DMODEL) - mu * mu;  // ddof=0, matches jnp.var
  const float rs  = rsqrtf(var + 1e-5f);
  f4v gv = *(const f4v*)&g[tid * 4];
  f4v bv = *(const f4v*)&bta[tid * 4];
  float o[4];
#pragma unroll
  for (int i = 0; i < 4; ++i) o[i] = (v[i] - mu) * rs * gv[i] + bv[i];
  if (WF32) {
    f4v ov = {o[0], o[1], o[2], o[3]};
    *(f4v*)&y[base] = ov;
  }
  if (WSPLIT) {
    u16x4 hv, lv;
#pragma unroll
    for (int i = 0; i < 4; ++i) {
      hv[i] = f2bf(o[i]);
      lv[i] = f2bf(o[i] - bf2f(hv[i]));
    }
    *(u16x4*)&yhi[base] = hv;
    *(u16x4*)&ylo[base] = lv;
  }
  if (WPLAIN) {
    u16x4 bb;
#pragma unroll
    for (int i = 0; i < 4; ++i) bb[i] = f2bf(o[i]);
    *(u16x4*)&yb[base] = bb;
  }
}

// ---------------- fp32 -> bf16 conversions (weights) ------------------------
__global__ __launch_bounds__(256)
void convert_split(const float* __restrict__ src, u16* __restrict__ hi,
                   u16* __restrict__ lo) {
  const size_t i = ((size_t)blockIdx.x * 256 + threadIdx.x) * 4;
  f4v v = *(const f4v*)&src[i];
  u16x4 hv, lv;
#pragma unroll
  for (int j = 0; j < 4; ++j) {
    hv[j] = f2bf(v[j]);
    lv[j] = f2bf(v[j] - bf2f(hv[j]));
  }
  *(u16x4*)&hi[i] = hv;
  *(u16x4*)&lo[i] = lv;
}

__global__ __launch_bounds__(256)
void convert_bf16(const float* __restrict__ src, u16* __restrict__ dst) {
  const size_t i = ((size_t)blockIdx.x * 256 + threadIdx.x) * 4;
  f4v v = *(const f4v*)&src[i];
  u16x4 b;
#pragma unroll
  for (int j = 0; j < 4; ++j) b[j] = f2bf(v[j]);
  *(u16x4*)&dst[i] = b;
}

// ---------------- split-bf16 MFMA GEMM: C = A*B^T (3-term hi/lo) ------------
// 128x128 tile, BK=32, 4 waves (2x2), 4x4 16x16x32 frags/wave, 48 MFMA/step.
template<bool RESID>
__global__ __launch_bounds__(256)
void gemm_split(const u16* __restrict__ Ah, const u16* __restrict__ Al,
                const u16* __restrict__ Bh, const u16* __restrict__ Bl,
                float* __restrict__ C, const float* __restrict__ resid,
                int N, int K) {
  __shared__ u16 sA[2][128 * 32];
  __shared__ u16 sB[2][128 * 32];
  const int t = threadIdx.x;
  const int m0 = blockIdx.y * 128, n0 = blockIdx.x * 128;
  const int srow = t >> 2, scol = (t & 3) * 8;
  const size_t ga0 = (size_t)(m0 + srow) * K + scol;
  const size_t ga1 = (size_t)(m0 + 64 + srow) * K + scol;
  const size_t gb0 = (size_t)(n0 + srow) * K + scol;
  const size_t gb1 = (size_t)(n0 + 64 + srow) * K + scol;
  const int ld0 = srow * 32 + scol;
  const int ld1 = (64 + srow) * 32 + scol;
  const int w = t >> 6, lane = t & 63;
  const int wr = (w >> 1) * 64, wc = (w & 1) * 64;
  const int lr = lane & 15, lk = (lane >> 4) * 8;
  f32x4 acc[4][4] = {};
  for (int k0 = 0; k0 < K; k0 += 32) {
    async16(&sA[0][ld0], Ah + ga0 + k0);
    async16(&sA[0][ld1], Ah + ga1 + k0);
    async16(&sA[1][ld0], Al + ga0 + k0);
    async16(&sA[1][ld1], Al + ga1 + k0);
    async16(&sB[0][ld0], Bh + gb0 + k0);
    async16(&sB[0][ld1], Bh + gb1 + k0);
    async16(&sB[1][ld0], Bl + gb0 + k0);
    async16(&sB[1][ld1], Bl + gb1 + k0);
    __syncthreads();
    bf16x8 ah[4], al[4], bh[4], bl[4];
#pragma unroll
    for (int m = 0; m < 4; ++m) {
      ah[m] = *(const bf16x8*)&sA[0][(wr + m * 16 + lr) * 32 + lk];
      al[m] = *(const bf16x8*)&sA[1][(wr + m * 16 + lr) * 32 + lk];
    }
#pragma unroll
    for (int n = 0; n < 4; ++n) {
      bh[n] = *(const bf16x8*)&sB[0][(wc + n * 16 + lr) * 32 + lk];
      bl[n] = *(const bf16x8*)&sB[1][(wc + n * 16 + lr) * 32 + lk];
    }
#pragma unroll
    for (int m = 0; m < 4; ++m)
#pragma unroll
      for (int n = 0; n < 4; ++n) {
        acc[m][n] = __builtin_amdgcn_mfma_f32_16x16x32_bf16(al[m], bh[n], acc[m][n], 0, 0, 0);
        acc[m][n] = __builtin_amdgcn_mfma_f32_16x16x32_bf16(ah[m], bl[n], acc[m][n], 0, 0, 0);
        acc[m][n] = __builtin_amdgcn_mfma_f32_16x16x32_bf16(ah[m], bh[n], acc[m][n], 0, 0, 0);
      }
    __syncthreads();
  }
  const int crow = (lane >> 4) * 4;  // D: col=lane&15, row=(lane>>4)*4+reg [m89]
#pragma unroll
  for (int m = 0; m < 4; ++m)
#pragma unroll
    for (int r = 0; r < 4; ++r) {
      const int row = m0 + wr + m * 16 + crow + r;
#pragma unroll
      for (int n = 0; n < 4; ++n) {
        const int col = n0 + wc + n * 16 + lr;
        const size_t o = (size_t)row * N + col;
        float v = acc[m][n][r];
        if (RESID) v += resid[o];
        C[o] = v;
      }
    }
}

// ---------------- qkv GEMM: split-bf16 MFMA with attention-layout epilogue --
// C cols: [0,1024)=Q -> Qh/Ql [bh][s][64]; [1024,2048)=K -> KhT/KlT swizzled
// 64x64 tiles [bh][kt][4096]; [2048,3072)=V -> VtT transposed swizzled tiles.
// Swizzle: elem (row,c) stored at c ^ ((row&7)<<3)  (bytes: ^ (row&7)<<4).
__global__ __launch_bounds__(256)
void gemm_qkv(const u16* __restrict__ Ah, const u16* __restrict__ Al,
              const u16* __restrict__ Bh, const u16* __restrict__ Bl,
              u16* __restrict__ Qh, u16* __restrict__ Ql,
              u16* __restrict__ KhT, u16* __restrict__ KlT,
              u16* __restrict__ VtT) {
  const int K = DMODEL;
  __shared__ u16 sA[2][128 * 32];
  __shared__ u16 sB[2][128 * 32];
  const int t = threadIdx.x;
  const int m0 = blockIdx.y * 128, n0 = blockIdx.x * 128;
  const int srow = t >> 2, scol = (t & 3) * 8;
  const size_t ga0 = (size_t)(m0 + srow) * K + scol;
  const size_t ga1 = (size_t)(m0 + 64 + srow) * K + scol;
  const size_t gb0 = (size_t)(n0 + srow) * K + scol;
  const size_t gb1 = (size_t)(n0 + 64 + srow) * K + scol;
  const int ld0 = srow * 32 + scol;
  const int ld1 = (64 + srow) * 32 + scol;
  const int w = t >> 6, lane = t & 63;
  const int wr = (w >> 1) * 64, wc = (w & 1) * 64;
  const int lr = lane & 15, lk = (lane >> 4) * 8;
  f32x4 acc[4][4] = {};
  for (int k0 = 0; k0 < K; k0 += 32) {
    async16(&sA[0][ld0], Ah + ga0 + k0);
    async16(&sA[0][ld1], Ah + ga1 + k0);
    async16(&sA[1][ld0], Al + ga0 + k0);
    async16(&sA[1][ld1], Al + ga1 + k0);
    async16(&sB[0][ld0], Bh + gb0 + k0);
    async16(&sB[0][ld1], Bh + gb1 + k0);
    async16(&sB[1][ld0], Bl + gb0 + k0);
    async16(&sB[1][ld1], Bl + gb1 + k0);
    __syncthreads();
    bf16x8 ah[4], al[4], bh[4], bl[4];
#pragma unroll
    for (int m = 0; m < 4; ++m) {
      ah[m] = *(const bf16x8*)&sA[0][(wr + m * 16 + lr) * 32 + lk];
      al[m] = *(const bf16x8*)&sA[1][(wr + m * 16 + lr) * 32 + lk];
    }
#pragma unroll
    for (int n = 0; n < 4; ++n) {
      bh[n] = *(const bf16x8*)&sB[0][(wc + n * 16 + lr) * 32 + lk];
      bl[n] = *(const bf16x8*)&sB[1][(wc + n * 16 + lr) * 32 + lk];
    }
#pragma unroll
    for (int m = 0; m < 4; ++m)
#pragma unroll
      for (int n = 0; n < 4; ++n) {
        acc[m][n] = __builtin_amdgcn_mfma_f32_16x16x32_bf16(al[m], bh[n], acc[m][n], 0, 0, 0);
        acc[m][n] = __builtin_amdgcn_mfma_f32_16x16x32_bf16(ah[m], bl[n], acc[m][n], 0, 0, 0);
        acc[m][n] = __builtin_amdgcn_mfma_f32_16x16x32_bf16(ah[m], bh[n], acc[m][n], 0, 0, 0);
      }
    __syncthreads();
  }
  const int crow = (lane >> 4) * 4;
#pragma unroll
  for (int m = 0; m < 4; ++m)
#pragma unroll
    for (int r = 0; r < 4; ++r) {
      const int row = m0 + wr + m * 16 + crow + r;   // token 0..4095
      const int bt = row >> 11, s = row & 2047;
#pragma unroll
      for (int n = 0; n < 4; ++n) {
        const int col = n0 + wc + n * 16 + lr;
        const float v = acc[m][n][r];
        const u16 hv = f2bf(v);
        const u16 lv = f2bf(v - bf2f(hv));
        if (col < 1024) {                       // Q, head-major rows
          const int hh = col >> 6, d = col & 63;
          const size_t o = ((size_t)(bt * NH + hh) * SEQ + s) * 64 + d;
          Qh[o] = hv; Ql[o] = lv;
        } else if (col < 2048) {                // K, swizzled [k][d] tiles
          const int c = col - 1024;
          const int hh = c >> 6, d = c & 63;
          const int kt = s >> 6, rk = s & 63;
          const size_t o = ((size_t)((bt * NH + hh) * 32 + kt)) * 4096 +
                           rk * 64 + (d ^ ((rk & 7) << 3));
          KhT[o] = hv; KlT[o] = lv;
        } else {                                // V, swizzled [d][k] tiles
          const int c = col - 2048;
          const int hh = c >> 6, d = c & 63;
          const int kt = s >> 6, kk = s & 63;
          const size_t o = ((size_t)((bt * NH + hh) * 32 + kt)) * 4096 +
                           d * 64 + (kk ^ ((d & 7) << 3));
          VtT[o] = hv;                          // V plain bf16 (PV error budget)
        }
      }
    }
}

// ---------------- MFMA flash attention ------------------------------------
// Block = (qt,h,b): 64 q-rows, 4 waves x 16 q-rows. K-tiles of 64, causal.
// QK^T split-bf16 (scores fp32-exact); PV plain bf16. Online softmax in regs.
__global__ __launch_bounds__(256)
void attn_mfma(const u16* __restrict__ Qh, const u16* __restrict__ Ql,
               const u16* __restrict__ KhT, const u16* __restrict__ KlT,
               const u16* __restrict__ VtT, u16* __restrict__ ctx_hi,
               u16* __restrict__ ctx_lo) {
  const int bx = blockIdx.x;
  const int qt = (bx & 1) ? (31 - (bx >> 1)) : (bx >> 1);  // causal load balance
  const int h = blockIdx.y, b = blockIdx.z;
  const int bh = b * NH + h;
  __shared__ u16 sKh[4096], sKl[4096], sVt[4096];  // 8KB each, swizzled images
  __shared__ u16 sP[4][1024];                      // per-wave P: 16q x 64k
  const int t = threadIdx.x;
  const int w = t >> 6, lane = t & 63;
  const int lr = lane & 15, hi16 = lane >> 4;
  const int lk = hi16 * 8;
  // Q fragments (A-operand: row=lane&15, inner d=(lane>>4)*8), hoisted.
  bf16x8 qh[2], ql[2];
  const size_t qrow = (size_t)(bh * SEQ + qt * 64 + w * 16 + lr) * 64;
#pragma unroll
  for (int ks = 0; ks < 2; ++ks) {
    qh[ks] = *(const bf16x8*)&Qh[qrow + ks * 32 + lk];
    ql[ks] = *(const bf16x8*)&Ql[qrow + ks * 32 + lk];
  }
  f32x4 O[4] = {};
  float mrow[4], lrow[4];
#pragma unroll
  for (int r = 0; r < 4; ++r) { mrow[r] = -1e30f; lrow[r] = 0.f; }
  const int ld16 = t * 8;  // linear LDS dest (t*16B) for global_load_lds

  for (int kt = 0; kt <= qt; ++kt) {
    __syncthreads();                       // all waves done reading prev tiles
    const size_t tb = (size_t)(bh * 32 + kt) * 4096;
    async16(&sKh[ld16],        KhT + tb + ld16);
    async16(&sKh[2048 + ld16], KhT + tb + 2048 + ld16);
    async16(&sKl[ld16],        KlT + tb + ld16);
    async16(&sKl[2048 + ld16], KlT + tb + 2048 + ld16);
    async16(&sVt[ld16],        VtT + tb + ld16);
    async16(&sVt[2048 + ld16], VtT + tb + 2048 + ld16);
    __syncthreads();                       // staging complete (vmcnt drained)

    // S = Q K^T (split-bf16, 3 terms)
    f32x4 S[4] = {};
#pragma unroll
    for (int ks = 0; ks < 2; ++ks) {
      const int kk = ks * 32 + lk;
      bf16x8 kbh[4], kbl[4];
#pragma unroll
      for (int n = 0; n < 4; ++n) {
        const int row = n * 16 + lr;       // key row
        const int off = row * 64 + (kk ^ ((row & 7) << 3));
        kbh[n] = *(const bf16x8*)&sKh[off];
        kbl[n] = *(const bf16x8*)&sKl[off];
      }
#pragma unroll
      for (int n = 0; n < 4; ++n) {
        S[n] = __builtin_amdgcn_mfma_f32_16x16x32_bf16(ql[ks], kbh[n], S[n], 0, 0, 0);
        S[n] = __builtin_amdgcn_mfma_f32_16x16x32_bf16(qh[ks], kbl[n], S[n], 0, 0, 0);
        S[n] = __builtin_amdgcn_mfma_f32_16x16x32_bf16(qh[ks], kbh[n], S[n], 0, 0, 0);
      }
    }
    // scale + causal mask (diag tile only); D layout: q=(lane>>4)*4+r, k=n*16+lr
    float p[4][4];
    const bool diag = (kt == qt);
#pragma unroll
    for (int n = 0; n < 4; ++n) {
      const int kloc = n * 16 + lr;
#pragma unroll
      for (int r = 0; r < 4; ++r) {
        float sv = S[n][r] * 0.125f;       // 1/sqrt(64)
        if (diag && kloc > w * 16 + hi16 * 4 + r) sv = -1e30f;
        p[n][r] = sv;
      }
    }
    // online softmax per q-row (reduce over n and the 16-lane group)
#pragma unroll
    for (int r = 0; r < 4; ++r) {
      float rm = fmaxf(fmaxf(p[0][r], p[1][r]), fmaxf(p[2][r], p[3][r]));
#pragma unroll
      for (int off = 1; off < 16; off <<= 1) rm = fmaxf(rm, __shfl_xor(rm, off));
      const float mnew = fmaxf(mrow[r], rm);
      const float corr = __expf(mrow[r] - mnew);
      mrow[r] = mnew;
      float su = 0.f;
#pragma unroll
      for (int n = 0; n < 4; ++n) { p[n][r] = __expf(p[n][r] - mnew); su += p[n][r]; }
#pragma unroll
      for (int off = 1; off < 16; off <<= 1) su += __shfl_xor(su, off);
      lrow[r] = lrow[r] * corr + su;
#pragma unroll
      for (int n = 0; n < 4; ++n) O[n][r] *= corr;
    }
    // P -> LDS (bf16, swizzled), then PV via MFMA
#pragma unroll
    for (int n = 0; n < 4; ++n) {
      const int k = n * 16 + lr;
#pragma unroll
      for (int r = 0; r < 4; ++r) {
        const int q = hi16 * 4 + r;
        sP[w][q * 64 + (k ^ ((q & 7) << 3))] = f2bf(p[n][r]);
      }
    }
    __syncthreads();                       // P visible (lgkm ordering)
#pragma unroll
    for (int ks = 0; ks < 2; ++ks) {
      const int kk = ks * 32 + lk;
      const bf16x8 pa = *(const bf16x8*)&sP[w][lr * 64 + (kk ^ ((lr & 7) << 3))];
      bf16x8 vb[4];
#pragma unroll
      for (int n = 0; n < 4; ++n) {
        const int d = n * 16 + lr;
        vb[n] = *(const bf16x8*)&sVt[d * 64 + (kk ^ ((d & 7) << 3))];
      }
#pragma unroll
      for (int n = 0; n < 4; ++n)
        O[n] = __builtin_amdgcn_mfma_f32_16x16x32_bf16(pa, vb[n], O[n], 0, 0, 0);
    }
  }
  // epilogue: O /= l, write ctx split hi/lo (token-major for proj GEMM)
#pragma unroll
  for (int r = 0; r < 4; ++r) {
    const float inv = 1.0f / lrow[r];
    const int qg = qt * 64 + w * 16 + hi16 * 4 + r;
    const size_t base = (size_t)(b * SEQ + qg) * DMODEL + h * 64;
#pragma unroll
    for (int n = 0; n < 4; ++n) {
      const float v = O[n][r] * inv;
      const u16 hv = f2bf(v);
      ctx_hi[base + n * 16 + lr] = hv;
      ctx_lo[base + n * 16 + lr] = f2bf(v - bf2f(hv));
    }
  }
}

// ---------------- router: fp32 gate logits + top-2 + list build -------------
__global__ __launch_bounds__(256)
void gate_kernel(const float* __restrict__ m, const float* __restrict__ gw,
                 int* __restrict__ epos, int* __restrict__ toklist,
                 float* __restrict__ wlist) {
  const int tid = threadIdx.x;
  const int t = blockIdx.x * 4 + (tid >> 6);
  const int lane = tid & 63;
  float part[NE] = {};
  for (int d0 = lane * 4; d0 < DMODEL; d0 += 256) {
    f4v mv = *(const f4v*)&m[(size_t)t * DMODEL + d0];
#pragma unroll
    for (int e = 0; e < NE; ++e) {
      f4v gv = *(const f4v*)&gw[e * DMODEL + d0];
      part[e] += mv[0]*gv[0] + mv[1]*gv[1] + mv[2]*gv[2] + mv[3]*gv[3];
    }
  }
#pragma unroll
  for (int e = 0; e < NE; ++e)
#pragma unroll
    for (int off = 32; off > 0; off >>= 1) part[e] += __shfl_xor(part[e], off);
  if (lane == 0) {
    int e0 = 0; float v0 = part[0];
#pragma unroll
    for (int e = 1; e < NE; ++e) if (part[e] > v0) { v0 = part[e]; e0 = e; }
    int e1 = -1; float v1 = -3.4e38f;
#pragma unroll
    for (int e = 0; e < NE; ++e)
      if (e != e0 && part[e] > v1) { v1 = part[e]; e1 = e; }
    const float w0 = 1.0f / (1.0f + __expf(v1 - v0));
    const float w1 = 1.0f - w0;
    int p0 = atomicAdd(&epos[e0], 1);
    toklist[e0 * 4096 + p0] = t; wlist[e0 * 4096 + p0] = w0;
    int p1 = atomicAdd(&epos[e1], 1);
    toklist[e1 * 4096 + p1] = t; wlist[e1 * 4096 + p1] = w1;
  }
}

__global__ void zero_epos(int* __restrict__ p) { p[threadIdx.x] = 0; }

__global__ void prefix_loss(const int* __restrict__ epos, int* __restrict__ eoff,
                            float* __restrict__ lossout) {
  int off = 0;
  float c[NE], sum = 0.f;
  for (int e = 0; e < NE; ++e) {
    eoff[e] = off; off += epos[e];
    c[e] = (float)epos[e]; sum += c[e];
  }
  const float mean = sum / NE;
  float var = 0.f;
  for (int e = 0; e < NE; ++e) var += (c[e] - mean) * (c[e] - mean);
  var *= (1.0f / (NE - 1));  // ddof=1
  lossout[0] = 0.01f * sqrtf(var) / (mean + 1e-6f);
}

// ---------------- expert fc1: h1 = gelu(gather(m_bf16) @ fc1_bf16[e]^T) -----
__global__ __launch_bounds__(256)
void gemm_fc1(const u16* __restrict__ mb, const u16* __restrict__ fc1b,
              const int* __restrict__ toklist, const int* __restrict__ epos,
              const int* __restrict__ eoff, u16* __restrict__ h1) {
  const int e = blockIdx.z;
  const int cnt = epos[e];
  const int m0 = blockIdx.y * 128;
  if (m0 >= cnt) return;
  const int n0 = blockIdx.x * 128;
  __shared__ u16 sA[128 * 32];
  __shared__ u16 sB[128 * 32];
  const int t = threadIdx.x;
  const int srow = t >> 2, scol = (t & 3) * 8;
  const int p0 = m0 + srow, p1 = m0 + 64 + srow;
  const int tok0 = toklist[e * 4096 + (p0 < cnt ? p0 : cnt - 1)];
  const int tok1 = toklist[e * 4096 + (p1 < cnt ? p1 : cnt - 1)];
  const size_t ga0 = (size_t)tok0 * DMODEL + scol;
  const size_t ga1 = (size_t)tok1 * DMODEL + scol;
  const size_t gb0 = (size_t)e * DFF * DMODEL + (size_t)(n0 + srow) * DMODEL + scol;
  const size_t gb1 = gb0 + (size_t)64 * DMODEL;
  const int ld0 = srow * 32 + scol;
  const int ld1 = (64 + srow) * 32 + scol;
  const int w = t >> 6, lane = t & 63;
  const int wr = (w >> 1) * 64, wc = (w & 1) * 64;
  const int lr = lane & 15, lk = (lane >> 4) * 8;
  f32x4 acc[4][4] = {};
  for (int k0 = 0; k0 < DMODEL; k0 += 32) {
    async16(&sA[ld0], mb + ga0 + k0);
    async16(&sA[ld1], mb + ga1 + k0);
    async16(&sB[ld0], fc1b + gb0 + k0);
    async16(&sB[ld1], fc1b + gb1 + k0);
    __syncthreads();
    bf16x8 a[4], bb[4];
#pragma unroll
    for (int m = 0; m < 4; ++m) a[m] = *(const bf16x8*)&sA[(wr + m * 16 + lr) * 32 + lk];
#pragma unroll
    for (int n = 0; n < 4; ++n) bb[n] = *(const bf16x8*)&sB[(wc + n * 16 + lr) * 32 + lk];
#pragma unroll
    for (int m = 0; m < 4; ++m)
#pragma unroll
      for (int n = 0; n < 4; ++n)
        acc[m][n] = __builtin_amdgcn_mfma_f32_16x16x32_bf16(a[m], bb[n], acc[m][n], 0, 0, 0);
    __syncthreads();
  }
  const int base = eoff[e];
  const int crow = (lane >> 4) * 4;
#pragma unroll
  for (int m = 0; m < 4; ++m)
#pragma unroll
    for (int r = 0; r < 4; ++r) {
      const int pr = m0 + wr + m * 16 + crow + r;
      if (pr < cnt) {
#pragma unroll
        for (int n = 0; n < 4; ++n) {
          const int col = n0 + wc + n * 16 + lr;
          h1[(size_t)(base + pr) * DFF + col] = f2bf(gelu_tanh(acc[m][n][r]));
        }
      }
    }
}

// ---------------- expert fc2: out += w * (h1 @ fc2_bf16[e]^T) ---------------
__global__ __launch_bounds__(256)
void gemm_fc2(const u16* __restrict__ h1, const u16* __restrict__ fc2b,
              const int* __restrict__ toklist, const float* __restrict__ wlist,
              const int* __restrict__ epos, const int* __restrict__ eoff,
              float* __restrict__ out) {
  const int e = blockIdx.z;
  const int cnt = epos[e];
  const int m0 = blockIdx.y * 128;
  if (m0 >= cnt) return;
  const int n0 = blockIdx.x * 128;
  __shared__ u16 sA[128 * 32];
  __shared__ u16 sB[128 * 32];
  const int t = threadIdx.x;
  const int srow = t >> 2, scol = (t & 3) * 8;
  const int base = eoff[e];
  const size_t ga0 = (size_t)(base + m0 + srow) * DFF + scol;
  const size_t ga1 = ga0 + (size_t)64 * DFF;
  const size_t gb0 = (size_t)e * DMODEL * DFF + (size_t)(n0 + srow) * DFF + scol;
  const size_t gb1 = gb0 + (size_t)64 * DFF;
  const int ld0 = srow * 32 + scol;
  const int ld1 = (64 + srow) * 32 + scol;
  const int w = t >> 6, lane = t & 63;
  const int wr = (w >> 1) * 64, wc = (w & 1) * 64;
  const int lr = lane & 15, lk = (lane >> 4) * 8;
  f32x4 acc[4][4] = {};
  for (int k0 = 0; k0 < DFF; k0 += 32) {
    async16(&sA[ld0], h1 + ga0 + k0);
    async16(&sA[ld1], h1 + ga1 + k0);
    async16(&sB[ld0], fc2b + gb0 + k0);
    async16(&sB[ld1], fc2b + gb1 + k0);
    __syncthreads();
    bf16x8 a[4], bb[4];
#pragma unroll
    for (int m = 0; m < 4; ++m) a[m] = *(const bf16x8*)&sA[(wr + m * 16 + lr) * 32 + lk];
#pragma unroll
    for (int n = 0; n < 4; ++n) bb[n] = *(const bf16x8*)&sB[(wc + n * 16 + lr) * 32 + lk];
#pragma unroll
    for (int m = 0; m < 4; ++m)
#pragma unroll
      for (int n = 0; n < 4; ++n)
        acc[m][n] = __builtin_amdgcn_mfma_f32_16x16x32_bf16(a[m], bb[n], acc[m][n], 0, 0, 0);
    __syncthreads();
  }
  const int crow = (lane >> 4) * 4;
#pragma unroll
  for (int m = 0; m < 4; ++m)
#pragma unroll
    for (int r = 0; r < 4; ++r) {
      const int pr = m0 + wr + m * 16 + crow + r;
      if (pr < cnt) {
        const int tok = toklist[e * 4096 + pr];
        const float wgt = wlist[e * 4096 + pr];
        float* dst = out + (size_t)tok * DMODEL + n0 + wc;
#pragma unroll
        for (int n = 0; n < 4; ++n)
          atomicAdd(&dst[n * 16 + lr], wgt * acc[m][n][r]);
      }
    }
}

// ---------------------------------------------------------------------------
extern "C" void kernel_launch(void* const* d_in, const int* in_sizes, int n_in,
                              void* d_out, int out_size, void* d_ws, size_t ws_size,
                              hipStream_t stream) {
  const float* x     = (const float*)d_in[0];
  const float* ln1g  = (const float*)d_in[1];
  const float* ln1b  = (const float*)d_in[2];
  const float* wqkv  = (const float*)d_in[3];
  const float* wproj = (const float*)d_in[4];
  const float* ln2g  = (const float*)d_in[5];
  const float* ln2b  = (const float*)d_in[6];
  const float* gw    = (const float*)d_in[7];
  const float* fc1   = (const float*)d_in[8];
  const float* fc2   = (const float*)d_in[9];
  float* out = (float*)d_out;

  char* p = (char*)d_ws;
  auto alloc = [&](size_t bytes) {
    void* r = (void*)p;
    p += (bytes + 255) & ~(size_t)255;
    return r;
  };
  u16*   h_hi    = (u16*)alloc((size_t)NTOK * DMODEL * 2);
  u16*   h_lo    = (u16*)alloc((size_t)NTOK * DMODEL * 2);
  u16*   Qh      = (u16*)alloc((size_t)NTOK * DMODEL * 2);
  u16*   Ql      = (u16*)alloc((size_t)NTOK * DMODEL * 2);
  u16*   KhT     = (u16*)alloc((size_t)NTOK * DMODEL * 2);
  u16*   KlT     = (u16*)alloc((size_t)NTOK * DMODEL * 2);
  u16*   VtT     = (u16*)alloc((size_t)NTOK * DMODEL * 2);
  u16*   ctx_hi  = (u16*)alloc((size_t)NTOK * DMODEL * 2);
  u16*   ctx_lo  = (u16*)alloc((size_t)NTOK * DMODEL * 2);
  float* m_f32   = (float*)alloc((size_t)NTOK * DMODEL * 4);
  u16*   m_bf16  = (u16*)alloc((size_t)NTOK * DMODEL * 2);
  u16*   wqkv_hi = (u16*)alloc((size_t)3 * DMODEL * DMODEL * 2);
  u16*   wqkv_lo = (u16*)alloc((size_t)3 * DMODEL * DMODEL * 2);
  u16*   wproj_hi= (u16*)alloc((size_t)DMODEL * DMODEL * 2);
  u16*   wproj_lo= (u16*)alloc((size_t)DMODEL * DMODEL * 2);
  u16*   fc1b    = (u16*)alloc((size_t)NE * DFF * DMODEL * 2);
  u16*   fc2b    = (u16*)alloc((size_t)NE * DMODEL * DFF * 2);
  u16*   h1      = (u16*)alloc((size_t)(2 * NTOK + 128) * DFF * 2);
  float* wlist   = (float*)alloc((size_t)NE * 4096 * 4);
  int*   toklist = (int*)alloc((size_t)NE * 4096 * 4);
  int*   epos    = (int*)alloc(64);
  int*   eoff    = (int*)alloc(64);

  zero_epos<<<1, 8, 0, stream>>>(epos);
  convert_split<<<3 * DMODEL * DMODEL / 1024, 256, 0, stream>>>(wqkv, wqkv_hi, wqkv_lo);
  convert_split<<<DMODEL * DMODEL / 1024, 256, 0, stream>>>(wproj, wproj_hi, wproj_lo);
  convert_bf16<<<NE * DFF * DMODEL / 1024, 256, 0, stream>>>(fc1, fc1b);
  convert_bf16<<<NE * DMODEL * DFF / 1024, 256, 0, stream>>>(fc2, fc2b);

  // LN1 -> split bf16
  ln_kernel<false, true, false><<<NTOK, 256, 0, stream>>>(x, ln1g, ln1b,
      nullptr, h_hi, h_lo, nullptr);
  // qkv GEMM, epilogue writes attention layouts directly
  gemm_qkv<<<dim3(24, 32), 256, 0, stream>>>(h_hi, h_lo, wqkv_hi, wqkv_lo,
                                             Qh, Ql, KhT, KlT, VtT);
  // MFMA flash attention
  attn_mfma<<<dim3(32, NH, 2), 256, 0, stream>>>(Qh, Ql, KhT, KlT, VtT,
                                                 ctx_hi, ctx_lo);
  // out = x + ctx @ wproj^T  (split-bf16 MFMA, resid add)
  gemm_split<true><<<dim3(8, 32), 256, 0, stream>>>(ctx_hi, ctx_lo, wproj_hi, wproj_lo,
                                                    out, x, DMODEL, DMODEL);
  // LN2 -> fp32 (gate) + plain bf16 (experts)
  ln_kernel<true, false, true><<<NTOK, 256, 0, stream>>>(out, ln2g, ln2b,
      m_f32, nullptr, nullptr, m_bf16);
  gate_kernel<<<NTOK / 4, 256, 0, stream>>>(m_f32, gw, epos, toklist, wlist);
  prefix_loss<<<1, 1, 0, stream>>>(epos, eoff, out + (size_t)NTOK * DMODEL);
  gemm_fc1<<<dim3(DFF / 128, 32, NE), 256, 0, stream>>>(m_bf16, fc1b, toklist,
                                                        epos, eoff, h1);
  gemm_fc2<<<dim3(DMODEL / 128, 32, NE), 256, 0, stream>>>(h1, fc2b, toklist, wlist,
                                                           epos, eoff, out);
}